// Round 18
// baseline (195.732 us; speedup 1.0000x reference)
//
#include <hip/hip_runtime.h>

// Problem constants
#define BB 2048
#define TT 3
#define VV 62
#define FF 5
#define HH 64

// Output layout (flat, return order): x_residual[2048*62*64], Sloss, dloss, S[2048*62*62]
#define XR_OFF 0
#define SL_OFF 8126464
#define DL_OFF 8126465
#define S_OFF  8126466

#define ALPHA_F 1e-4f
#define INV_SQRT310 0.05679618342470648f  // 1/sqrt(62*5)
#define INV_SQRT15  0.2581988897471611f   // 1/sqrt(3*5)

typedef float f32x2 __attribute__((ext_vector_type(2)));
typedef float f32x4 __attribute__((ext_vector_type(4)));
typedef _Float16 f16x4 __attribute__((ext_vector_type(4)));
typedef _Float16 f16x8 __attribute__((ext_vector_type(8)));

// compiler-ordering fence for wave-synchronous LDS phases
#define WFENCE() do { __builtin_amdgcn_wave_barrier(); __asm__ __volatile__("" ::: "memory"); } while (0)

// Prep (workspace f16, 21252 elems = 42504 B):
//  [0,12288)      tw -> f16 B-frags (16x16x32), as R8
//  [12288,13312)  Theta -> f16 B-frags (16x16x16)
//  [13312,17408)  Vs -> f16 A-frags (16x16x32), 0-padded m>=62 / k>=62
//  [17408,21252)  bsT f16: bsT[v*62+u] = bs[u*62+v]
__global__ void prep_kernel(const float* __restrict__ tw, const float* __restrict__ Theta,
                            const float* __restrict__ Vs, const float* __restrict__ bs,
                            _Float16* __restrict__ wh, float* __restrict__ out) {
    int i = blockIdx.x * 256 + threadIdx.x;
    if (i < 12288) {
        int t  = i / 4096, r2 = i - t * 4096;
        int ot = r2 >> 10, r3 = r2 & 1023;
        int kk = r3 >> 9,  r4 = r3 & 511;
        int l  = r4 >> 3,  j  = r4 & 7;
        int o  = ot * 16 + (l & 15);
        int c  = kk * 32 + ((l >> 4) << 3) + j;
        wh[i] = (_Float16)tw[o * 192 + c * 3 + t];
    } else if (i < 13312) {
        int ii = i - 12288;
        int ot = ii >> 8, r = ii & 255;
        int l  = r >> 2,  j = r & 3;
        int k  = ((l >> 4) << 2) + j;
        int o  = ot * 16 + (l & 15);
        wh[i] = (k < 15) ? (_Float16)Theta[k * 64 + o] : (_Float16)0.f;
    } else if (i < 17408) {
        int ii = i - 13312;
        int fr = ii >> 9;                 // mt*2+kk
        int mt = fr >> 1, kk = fr & 1;
        int r  = ii & 511;
        int l  = r >> 3, j = r & 7;
        int m  = mt * 16 + (l & 15);
        int k  = kk * 32 + ((l >> 4) << 3) + j;
        wh[i] = (m < 62 && k < 62) ? (_Float16)Vs[m * 62 + k] : (_Float16)0.f;
    } else if (i < 21252) {
        int ii = i - 17408;
        int v = ii / 62, u = ii - v * 62;
        wh[i] = (_Float16)bs[u * 62 + v];
    }
    if (i < 2) out[SL_OFF + i] = 0.f;
}

// NUMERIC CONTRACT: f16 allowed on gcn/G surface, C1/C2 MFMA inputs, and Sm inputs
// (Vs/sig/bs). Softmax itself stays f32.
__launch_bounds__(256)
__attribute__((amdgpu_waves_per_eu(3, 3)))   // pin RA to 85-VGPR budget (3 waves/SIMD)
__global__ void stgcn_kernel(
    const float* __restrict__ x,     const float* __restrict__ U1,
    const float* __restrict__ U2,    const float* __restrict__ U3,
    const float* __restrict__ be,    const float* __restrict__ Ve,
    const float* __restrict__ W1,    const float* __restrict__ W2,
    const float* __restrict__ W3,    const float* __restrict__ bs,
    const float* __restrict__ Vs,    const float* __restrict__ a,
    const float* __restrict__ Theta, const _Float16* __restrict__ Wh,
    const float* __restrict__ tb,    const float* __restrict__ rw,
    const float* __restrict__ rb,    const float* __restrict__ gamma_,
    const float* __restrict__ beta_, float* __restrict__ out)
{
    // LDS: 930 + 3844 + 3844 + 1132 = 9750 floats = 39,000 B -> 3 blocks/CU (VGPR-capped)
    __shared__ __align__(16) float sx[930];   // x[b] [t][v][f]
    __shared__ __align__(16) float sS[3844];  // sigT f16 [64][72] -> tmpS -> C1n(f32) ; F: sC1h/sPh2 | sGh
    __shared__ __align__(16) float sAt[3844]; // Sm(raw f32) -> C2(f32) ; F: sC2h f16 [0,8K)
    __shared__ __align__(16) float sU[1132];  // scratch union

    // stage B/C view of sU
    float* const sL    = sU;          // 186
    float* const sR    = sU + 186;    // 186
    float* const sR0   = sU + 372;    // 186
    float* const sRr   = sU + 558;    // 186
    float* const sy    = sU + 744;    // 15
    float* const sprod = sU + 759;    // 9
    float* const sE    = sU + 768;    // 9
    float* const stA   = sU + 777;    // 9
    // phase2/3/4 partials view (B/C scratch dead)
    float* const pMq   = sU;          // [4][64] per-wave col max   (written in Sm-MFMA block)
    float* const pSq   = sU + 256;    // [4][64] per-wave col expsum
    float* const pCp   = sU + 512;    // [4][64] colsum partials
    float* const pM    = sU + 768;    // 62 final col max
    float* const pInv  = sU + 832;    // 62 1/den
    // persistent tail of sU
    float* const sDiag = sU + 992;    // 62
    float* const scol  = sU + 1054;   // 62
    float* const sred  = sU + 1116;   // 16

    // overlays
    _Float16* const sigT = (_Float16*)sS;          // [64][72] f16 sig^T (B-operand for Sm-MFMA)
    _Float16* const sC1h = (_Float16*)sS;          // [64][64] f16 A-operand (C1n), bytes [0,8192)
    _Float16* const sC2h = (_Float16*)sAt;         // [64][64] f16 A-operand (C2)
    _Float16* const sPh2 = (_Float16*)sS;          // [64][64] f16 gcn staging (after sC1h dead)
    _Float16* const sGh  = (_Float16*)(sS + 2048); // [3][64][16] f16 G (A-operand for step2)
    _Float16* const XbT  = (_Float16*)sU;          // [16][64] f16 B-operand X^T (over dead pMq/pSq... NO — over dead B/C sL region only after Sm stats consumed; see build phase placement)

    const int b   = blockIdx.x;
    const int tid = threadIdx.x;
    const int o   = tid & 63;
    const int q   = tid >> 6;
    const int qu  = __builtin_amdgcn_readfirstlane(q);
    const int lane = o;
    const int lo  = lane & 15, hi = lane >> 4;

    // ---- stage A: loads (float2-vectorized) ----
    {
        const float2* xs = reinterpret_cast<const float2*>(x + (size_t)b * 930);
        float2* sd = reinterpret_cast<float2*>(sx);
        for (int i = tid; i < 465; i += 256) sd[i] = xs[i];
    }
    __syncthreads();

    // ---- stage B: temporal attention ----
    if (tid < 15) {
        int t = tid / 5, f = tid % 5;
        float s = 0.f;
        for (int v = 0; v < 62; ++v) s += sx[t * 310 + v * 5 + f] * U1[v];
        sy[tid] = s;
    }
    if (tid < 186) {
        int v = tid / 3, t = tid % 3;
        float s = 0.f, s0 = 0.f;
        #pragma unroll
        for (int f = 0; f < 5; ++f) {
            float xv = sx[t * 310 + v * 5 + f];
            s  += U3[f] * xv;
            s0 += W3[f] * xv;
        }
        sR[v * 3 + t]  = s;
        sR0[t * 62 + v] = s0;
    }
    __syncthreads();
    if (tid < 186) {
        int t = tid / 62, u = tid % 62;
        float s = 0.f;
        for (int f = 0; f < 5; ++f) s += sy[t * 5 + f] * U2[f * 62 + u];
        sL[t * 62 + u] = s;
    }
    __syncthreads();
    // prod -> E -> temporal softmax: wave-0-only, wave-synchronous
    if (tid < 64) {
        if (o < 9) {
            int t = o / 3, u = o - (o / 3) * 3;
            float s = 0.f;
            for (int v = 0; v < 62; ++v) s += sL[t * 62 + v] * sR[v * 3 + u];
            sprod[o] = s;
        }
        WFENCE();
        if (o < 9) {
            int t = o / 3, u = o - (o / 3) * 3;
            float s = 0.f;
            #pragma unroll
            for (int ss = 0; ss < 3; ++ss) {
                float p = sprod[ss * 3 + u] + be[ss * 3 + u];
                s += Ve[t * 3 + ss] * (1.f / (1.f + __expf(-p)));
            }
            sE[o] = s;
        }
        WFENCE();
        if (o < 3) {
            int u = o;
            float m = fmaxf(fmaxf(sE[u], sE[3 + u]), sE[6 + u]);
            float e0 = __expf(sE[u] - m);
            float e1 = __expf(sE[3 + u] - m);
            float e2 = __expf(sE[6 + u] - m);
            float inv = 1.f / (e0 + e1 + e2);
            stA[u]     = e0 * inv;
            stA[3 + u] = e1 * inv;
            stA[6 + u] = e2 * inv;
        }
    }
    __syncthreads();

    // ---- stage C: spatial attention (x_TAt factored out) ----
    if (tid < 186) {
        float w1t[3];
        #pragma unroll
        for (int t = 0; t < 3; ++t) {
            float s = 0.f;
            #pragma unroll
            for (int u = 0; u < 3; ++u) s += W1[u] * stA[t * 3 + u];
            w1t[t] = s;
        }
        int v = tid / 3, s3 = tid - v * 3;
        float s = 0.f;
        #pragma unroll
        for (int f = 0; f < 5; ++f) {
            float z = 0.f;
            #pragma unroll
            for (int t = 0; t < 3; ++t) z += sx[t * 310 + v * 5 + f] * w1t[t];
            s += z * W2[f * 3 + s3];
        }
        sL[v * 3 + s3] = s * INV_SQRT310;
        int u2 = tid / 62, v2 = tid - u2 * 62;
        float s2 = 0.f;
        #pragma unroll
        for (int t = 0; t < 3; ++t) s2 += stA[t * 3 + u2] * sR0[t * 62 + v2];
        sRr[u2 * 62 + v2] = s2 * INV_SQRT310;
    }
    __syncthreads();
    // sig[w][v] -> f16 TRANSPOSED sigT[v][w] (B-operand for Sm-MFMA); bsT coalesced
    {
        const _Float16* bsT = Wh + 17408;
        for (int i = tid; i < 3844; i += 256) {
            int v = i / 62, w = i - v * 62;
            float s = (float)bsT[i];                       // bsT[v*62+w] = bs[w*62+v]
            #pragma unroll
            for (int t = 0; t < 3; ++t) s += sL[w * 3 + t] * sRr[t * 62 + v];
            sigT[v * 72 + w] = (_Float16)(1.f / (1.f + __expf(-s)));
        }
        // zero K-pads w=62,63 for every row
        if (tid < 64) {
            sigT[tid * 72 + 62] = (_Float16)0.f;
            sigT[tid * 72 + 63] = (_Float16)0.f;
        }
    }
    __syncthreads();
    // ---- Sm = Vs·sig via MFMA, with softmax column stats folded in-register:
    //      wave qu holds ALL 16 u-rows (u=qu*16+hi*4+rg) of column v=nt*16+lo ->
    //      per-wave col max/expsum via shfl_xor(16/32) (replaces phase2 stats re-read). ----
    {
        const f16x8* VsAp = (const f16x8*)(Wh + 13312);
        f16x8 A0 = VsAp[(qu * 2 + 0) * 64 + lane];
        f16x8 A1 = VsAp[(qu * 2 + 1) * 64 + lane];
        #pragma unroll
        for (int nt = 0; nt < 4; ++nt) {
            f16x8 B0 = *(const f16x8*)(sigT + (nt * 16 + lo) * 72 + (hi << 3));
            f16x8 B1 = *(const f16x8*)(sigT + (nt * 16 + lo) * 72 + 32 + (hi << 3));
            f32x4 D = (f32x4){0.f, 0.f, 0.f, 0.f};
            D = __builtin_amdgcn_mfma_f32_16x16x32_f16(A0, B0, D, 0, 0, 0);
            D = __builtin_amdgcn_mfma_f32_16x16x32_f16(A1, B1, D, 0, 0, 0);
            int v  = nt * 16 + lo;
            int ub = qu * 16 + (hi << 2);
            #pragma unroll
            for (int rg = 0; rg < 4; ++rg) {
                if (ub + rg < 62 && v < 62) sAt[(ub + rg) * 62 + v] = D[rg];   // RAW Sm f32
            }
            // in-register column stats (valid-u only; invalid rows excluded)
            float mq = -1e30f;
            #pragma unroll
            for (int rg = 0; rg < 4; ++rg) mq = fmaxf(mq, (ub + rg < 62) ? D[rg] : -1e30f);
            mq = fmaxf(mq, __shfl_xor(mq, 16, 64));
            mq = fmaxf(mq, __shfl_xor(mq, 32, 64));
            float sq = 0.f;
            #pragma unroll
            for (int rg = 0; rg < 4; ++rg) if (ub + rg < 62) sq += __expf(D[rg] - mq);
            sq += __shfl_xor(sq, 16, 64);
            sq += __shfl_xor(sq, 32, 64);
            if (hi == 0 && v < 62) { pMq[qu * 64 + v] = mq; pSq[qu * 64 + v] = sq; }
        }
    }
    __syncthreads();

    // ---- phase 2: tmpS (column-mapped, colsum free) + dloss (stats now pre-computed) ----
    {
        int j = o;
        if (j < 62) {
            int i0 = qu * 16, i1 = (qu == 3) ? 62 : i0 + 16;
            float xj[5];
            #pragma unroll
            for (int f = 0; f < 5; ++f) xj[f] = sx[310 + j * 5 + f];
            float cp2 = 0.f;
            for (int i = i0; i < i1; ++i) {
                float s = 0.f;
                #pragma unroll
                for (int f = 0; f < 5; ++f)
                    s += fabsf(sx[310 + i * 5 + f] - xj[f]) * a[f];
                float e = __expf(fmaxf(s, 0.f));
                sS[i * 62 + j] = e;                        // tmpS overwrites sigT
                cp2 += e;
            }
            pCp[qu * 64 + j] = cp2;
        } else {
            int f = (o == 62) ? qu : (qu == 0 ? 4 : -1);
            if (f >= 0) {
                float su = 0.f, sq2 = 0.f;
                for (int v = 0; v < 62; ++v) {
                    float xv = sx[310 + v * 5 + f];
                    su += xv; sq2 += xv * xv;
                }
                sred[8 + f] = 124.f * sq2 - 2.f * su * su;
            }
        }
    }
    __syncthreads();
    // ---- phase 3: per-column combines ----
    if (tid < 62) {
        int v = tid;
        float m0 = pMq[v], m1 = pMq[64 + v], m2 = pMq[128 + v], m3 = pMq[192 + v];
        float M = fmaxf(fmaxf(m0, m1), fmaxf(m2, m3));
        float den = pSq[v] * __expf(m0 - M) + pSq[64 + v] * __expf(m1 - M)
                  + pSq[128 + v] * __expf(m2 - M) + pSq[192 + v] * __expf(m3 - M);
        pM[v]   = M;
        pInv[v] = 1.f / den;
        scol[v] = 1.f / (pCp[v] + pCp[64 + v] + pCp[128 + v] + pCp[192 + v]);
    }
    __syncthreads();
    // ---- phase 4: normalize S, fused softmax-At, C1n/C2 f32 in place, Sloss ----
    float slp = 0.f;
    for (int idx = tid; idx < 3844; idx += 256) {
        int i = idx / 62, j = idx - i * 62;
        float sv = sS[idx] * scol[j];
        out[S_OFF + (size_t)b * 3844 + idx] = sv;
        slp += sv * sv;
        float A = __expf(sAt[idx] - pM[j]) * pInv[j];
        if (i == j) sDiag[i] = A;
        sS[idx] = -sv * A;                              // C1 PRE-NEGATED (f32)
        float c2 = 2.f * sv * sv; if (i == j) c2 -= 1.f;
        sAt[idx] = c2 * A;                              // C2 (f32)
    }
    for (int m = 32; m > 0; m >>= 1) slp += __shfl_down(slp, m, 64);
    if ((tid & 63) == 0) sred[q] = slp;
    __syncthreads();
    if (tid == 0) {
        atomicAdd(out + SL_OFF, (sred[0] + sred[1] + sred[2] + sred[3]) * (ALPHA_F / 2048.f));
        float dl = sred[8] + sred[9] + sred[10] + sred[11] + sred[12];
        atomicAdd(out + DL_OFF, dl * ALPHA_F);
    }

    // ---- conversion: f32 C -> f16 swizzled A-operands, race-free 2-phase overlay (R14) ----
    {
        unsigned cp8[8];
        #pragma unroll
        for (int it = 0; it < 8; ++it) {
            int idx = tid + it * 256;                      // 0..2047
            union { _Float16 h[2]; unsigned u; } pk;
            pk.h[0] = (_Float16)sS[idx];
            pk.h[1] = (_Float16)sAt[idx];
            cp8[it] = pk.u;
        }
        __syncthreads();
        #pragma unroll
        for (int it = 0; it < 8; ++it) {
            int idx = tid + it * 256;
            int i = idx / 62, j = idx - i * 62;
            int ad = j * 64 + (i ^ ((j & 7) << 3));        // A-layout: row=v(j), k=u(i)
            union { _Float16 h[2]; unsigned u; } pk; pk.u = cp8[it];
            sC1h[ad] = pk.h[0];
            sC2h[ad] = pk.h[1];
        }
        #pragma unroll
        for (int it = 8; it < 16; ++it) {
            int idx = tid + it * 256;
            if (idx < 3844) {
                float c1 = sS[idx], c2v = sAt[idx];
                int i = idx / 62, j = idx - i * 62;
                int ad = j * 64 + (i ^ ((j & 7) << 3));
                sC1h[ad] = (_Float16)c1;
                sC2h[ad] = (_Float16)c2v;
            }
        }
        // zero the 2 unwritten k-slots (u=62,63) per row: no garbage into MFMA K-dim
        if (tid < 124) {
            int j = tid >> 1, i = 62 + (tid & 1);
            int ad = j * 64 + (i ^ ((j & 7) << 3));
            sC1h[ad] = (_Float16)0.f;
            sC2h[ad] = (_Float16)0.f;
        }
    }
    __syncthreads();

    // ---- build: XbT (f16 B-operand X^T) + g0 (f16) into sGh + kf=15 zero ----
    for (int i = tid; i < 930; i += 256) {
        int t = i / 310, r = i - t * 310, n = r / 5, f = r - n * 5;
        int tf = t * 5 + f;
        float xv = sx[i];
        XbT[tf * 64 + (n ^ ((tf & 7) << 3))] = (_Float16)xv;
        sGh[t * 1024 + n * 16 + f] = (_Float16)(sDiag[n] * xv);   // g0 = diag·x (kf 0..4)
    }
    if (tid < 192) {   // zero kf=15 for all rows (K-dim garbage guard for step2 MFMA)
        int t = tid >> 6, v = tid & 63;
        sGh[t * 1024 + v * 16 + 15] = (_Float16)0.f;
    }
    if (tid < 30) {                       // zero XbT k-holes u in {62,63}, rows tf 0..14
        int tf = tid >> 1, u2 = 62 + (tid & 1);
        XbT[tf * 64 + (u2 ^ ((tf & 7) << 3))] = (_Float16)0.f;
    }
    if (tid >= 64 && tid < 128) XbT[15 * 64 + (tid - 64)] = (_Float16)0.f;   // pad row tf=15
    __syncthreads();

    // ---- step1 as MFMA: G1 = C1n^T·X, G2 = C2^T·X, all 3 t at once (4 mfma/wave).
    //      D-scatter (f16, bytes >=8K) disjoint from A-reads (<8K): no intra-phase barrier. ----
    {
        int r0 = qu * 16 + lo;                // A row = v
        int sw = (r0 & 7) << 3;
        int cb = hi << 3;
        int bsw = (lo & 7) << 3;
        f32x4 D1 = (f32x4){0.f, 0.f, 0.f, 0.f};
        f32x4 D2 = (f32x4){0.f, 0.f, 0.f, 0.f};
        #pragma unroll
        for (int kk = 0; kk < 2; ++kk) {
            int ko = kk * 32 + cb;
            f16x8 Bf = *(const f16x8*)(XbT + lo * 64 + (ko ^ bsw));
            f16x8 A1 = *(const f16x8*)(sC1h + r0 * 64 + (ko ^ sw));
            f16x8 A2 = *(const f16x8*)(sC2h + r0 * 64 + (ko ^ sw));
            D1 = __builtin_amdgcn_mfma_f32_16x16x32_f16(A1, Bf, D1, 0, 0, 0);
            D2 = __builtin_amdgcn_mfma_f32_16x16x32_f16(A2, Bf, D2, 0, 0, 0);
        }
        int tf = lo;
        if (tf < 15) {
            int t = tf / 5, f = tf - (tf / 5) * 5;
            int vb = qu * 16 + (hi << 2);
            #pragma unroll
            for (int rg = 0; rg < 4; ++rg) {
                int v = vb + rg;
                if (v < 62) {
                    sGh[t * 1024 + v * 16 + 5 + f]  = (_Float16)D1[rg];
                    sGh[t * 1024 + v * 16 + 10 + f] = (_Float16)D2[rg];
                }
            }
        }
    }
    __syncthreads();

    // ---- stage F t-loop: step2 (MFMA 16x16x16: gcn = G·Theta) -> step3 (MFMA 16x16x32) ----
    const f16x8* Wp  = (const f16x8*)Wh;
    const _Float16* Thp = Wh + 12288;          // Theta B-frags (16x16x16 layout)
    f16x4 thB[4];
    #pragma unroll
    for (int ot = 0; ot < 4; ++ot)
        thB[ot] = *(const f16x4*)(Thp + ot * 256 + lane * 4);

    f32x4 acc[4];
    #pragma unroll
    for (int ot = 0; ot < 4; ++ot) acc[ot] = (f32x4){0.f, 0.f, 0.f, 0.f};

    for (int t = 0; t < 3; ++t) {
        // step2: wave qu owns M-tile qu. A = G rows qu*16.., K=16. 4 N-tiles.
        {
            f16x4 Ag = *(const f16x4*)(sGh + t * 1024 + (qu * 16 + lo) * 16 + (hi << 2));
            f32x4 Dg[4];
            #pragma unroll
            for (int ot = 0; ot < 4; ++ot) {
                f32x4 zero = (f32x4){0.f, 0.f, 0.f, 0.f};
                Dg[ot] = __builtin_amdgcn_mfma_f32_16x16x16f16(Ag, thB[ot], zero, 0, 0, 0);
            }
            // scatter: relu -> f16 -> sPh2 A-layout (rows 62,63 garbage, unused downstream)
            #pragma unroll
            for (int rg = 0; rg < 4; ++rg) {
                int v = qu * 16 + (hi << 2) + rg;
                int swv = (v & 7) << 3;
                #pragma unroll
                for (int ot = 0; ot < 4; ++ot) {
                    int oc = ot * 16 + lo;
                    sPh2[v * 64 + (oc ^ swv)] = (_Float16)fmaxf(Dg[ot][rg], 0.f);
                }
            }
        }
        __syncthreads();
        // step3: MFMA 16x16x32. Wave qu owns M-tile qu. K=64 = 2 kk-blocks.
        {
            int r0 = qu * 16 + lo;
            int cb = hi << 3;
            int sw = (r0 & 7) << 3;
            f16x8 A0 = *(const f16x8*)(sPh2 + r0 * 64 + ((cb) ^ sw));
            f16x8 A1 = *(const f16x8*)(sPh2 + r0 * 64 + ((32 + cb) ^ sw));
            #pragma unroll
            for (int ot = 0; ot < 4; ++ot) {
                f16x8 B0 = Wp[((t * 4 + ot) * 2 + 0) * 64 + lane];
                f16x8 B1 = Wp[((t * 4 + ot) * 2 + 1) * 64 + lane];
                acc[ot] = __builtin_amdgcn_mfma_f32_16x16x32_f16(A0, B0, acc[ot], 0, 0, 0);
                acc[ot] = __builtin_amdgcn_mfma_f32_16x16x32_f16(A1, B1, acc[ot], 0, 0, 0);
            }
        }
        if (t < 2) __syncthreads();   // protect next step2's sPh2 writes vs this step3's reads
    }

    // ---- fragment-direct epilogue: z + LayerNorm straight from acc registers ----
    {
        float rbv[4], tbv[4], gmv[4], btv[4], rww[4][5];
        #pragma unroll
        for (int ot = 0; ot < 4; ++ot) {
            int oo = ot * 16 + lo;
            rbv[ot] = rb[oo]; tbv[ot] = tb[oo];
            gmv[ot] = gamma_[oo]; btv[ot] = beta_[oo];
            #pragma unroll
            for (int f = 0; f < 5; ++f) rww[ot][f] = rw[oo * 5 + f];
        }
        float zst[4][4];                      // [rg][ot]
        float s1[4] = {0.f, 0.f, 0.f, 0.f};
        float s2[4] = {0.f, 0.f, 0.f, 0.f};
        #pragma unroll
        for (int rg = 0; rg < 4; ++rg) {
            int v = qu * 16 + hi * 4 + rg;    // may be 62/63 (wave 3): stores guarded below
            float x5[5];
            #pragma unroll
            for (int f = 0; f < 5; ++f) x5[f] = sx[v * 5 + f];   // x[:,0]
            #pragma unroll
            for (int ot = 0; ot < 4; ++ot) {
                float r = rbv[ot];
                #pragma unroll
                for (int f = 0; f < 5; ++f) r += x5[f] * rww[ot][f];
                float z = fmaxf(r + (acc[ot][rg] + tbv[ot]) * INV_SQRT15, 0.f);
                zst[rg][ot] = z;
                s1[rg] += z;
                s2[rg] += z * z;
            }
        }
        #pragma unroll
        for (int rg = 0; rg < 4; ++rg) {
            #pragma unroll
            for (int m = 1; m < 16; m <<= 1) {
                s1[rg] += __shfl_xor(s1[rg], m, 64);
                s2[rg] += __shfl_xor(s2[rg], m, 64);
            }
        }
        #pragma unroll
        for (int rg = 0; rg < 4; ++rg) {
            int v = qu * 16 + hi * 4 + rg;
            float mean = s1[rg] * 0.015625f;
            float var  = s2[rg] * 0.015625f - mean * mean;
            float inv  = rsqrtf(var + 1e-5f);
            if (v < 62) {
                #pragma unroll
                for (int ot = 0; ot < 4; ++ot) {
                    int oo = ot * 16 + lo;
                    out[XR_OFF + (size_t)b * 3968 + v * 64 + oo] =
                        (zst[rg][ot] - mean) * inv * gmv[ot] + btv[ot];
                }
            }
        }
    }
}

extern "C" void kernel_launch(void* const* d_in, const int* in_sizes, int n_in,
                              void* d_out, int out_size, void* d_ws, size_t ws_size,
                              hipStream_t stream) {
    const float* x   = (const float*)d_in[0];
    const float* U1  = (const float*)d_in[1];
    const float* U2  = (const float*)d_in[2];
    const float* U3  = (const float*)d_in[3];
    const float* be  = (const float*)d_in[4];
    const float* Ve  = (const float*)d_in[5];
    const float* W1  = (const float*)d_in[6];
    const float* W2  = (const float*)d_in[7];
    const float* W3  = (const float*)d_in[8];
    const float* bs  = (const float*)d_in[9];
    const float* Vs  = (const float*)d_in[10];
    const float* a   = (const float*)d_in[11];
    const float* Th  = (const float*)d_in[12];
    const float* tw  = (const float*)d_in[13];
    const float* tb  = (const float*)d_in[14];
    const float* rw  = (const float*)d_in[15];
    const float* rb  = (const float*)d_in[16];
    const float* gm  = (const float*)d_in[17];
    const float* bt  = (const float*)d_in[18];
    float* out = (float*)d_out;
    _Float16* wh = (_Float16*)d_ws;  // 21252 f16 = 42504 B (tw + Theta + VsA + bsT)

    prep_kernel<<<84, 256, 0, stream>>>(tw, Th, Vs, bs, wh, out);
    stgcn_kernel<<<2048, 256, 0, stream>>>(x, U1, U2, U3, be, Ve, W1, W2, W3,
                                           bs, Vs, a, Th, wh, tb, rw, rb, gm, bt, out);
}

// Round 19
// 193.074 us; speedup vs baseline: 1.0138x; 1.0138x over previous
//
#include <hip/hip_runtime.h>

// Problem constants
#define BB 2048
#define TT 3
#define VV 62
#define FF 5
#define HH 64

// Output layout (flat, return order): x_residual[2048*62*64], Sloss, dloss, S[2048*62*62]
#define XR_OFF 0
#define SL_OFF 8126464
#define DL_OFF 8126465
#define S_OFF  8126466

#define ALPHA_F 1e-4f
#define INV_SQRT310 0.05679618342470648f  // 1/sqrt(62*5)
#define INV_SQRT15  0.2581988897471611f   // 1/sqrt(3*5)

typedef float f32x2 __attribute__((ext_vector_type(2)));
typedef float f32x4 __attribute__((ext_vector_type(4)));
typedef _Float16 f16x4 __attribute__((ext_vector_type(4)));
typedef _Float16 f16x8 __attribute__((ext_vector_type(8)));

// compiler-ordering fence for wave-synchronous LDS phases
#define WFENCE() do { __builtin_amdgcn_wave_barrier(); __asm__ __volatile__("" ::: "memory"); } while (0)

// Prep (workspace f16, 21252 elems = 42504 B):
//  [0,12288)      tw -> f16 B-frags (16x16x32), as R8
//  [12288,13312)  Theta -> f16 B-frags (16x16x16)
//  [13312,17408)  Vs -> f16 A-frags (16x16x32), 0-padded m>=62 / k>=62
//  [17408,21252)  bsT f16: bsT[v*62+u] = bs[u*62+v]
__global__ void prep_kernel(const float* __restrict__ tw, const float* __restrict__ Theta,
                            const float* __restrict__ Vs, const float* __restrict__ bs,
                            _Float16* __restrict__ wh, float* __restrict__ out) {
    int i = blockIdx.x * 256 + threadIdx.x;
    if (i < 12288) {
        int t  = i / 4096, r2 = i - t * 4096;
        int ot = r2 >> 10, r3 = r2 & 1023;
        int kk = r3 >> 9,  r4 = r3 & 511;
        int l  = r4 >> 3,  j  = r4 & 7;
        int o  = ot * 16 + (l & 15);
        int c  = kk * 32 + ((l >> 4) << 3) + j;
        wh[i] = (_Float16)tw[o * 192 + c * 3 + t];
    } else if (i < 13312) {
        int ii = i - 12288;
        int ot = ii >> 8, r = ii & 255;
        int l  = r >> 2,  j = r & 3;
        int k  = ((l >> 4) << 2) + j;
        int o  = ot * 16 + (l & 15);
        wh[i] = (k < 15) ? (_Float16)Theta[k * 64 + o] : (_Float16)0.f;
    } else if (i < 17408) {
        int ii = i - 13312;
        int fr = ii >> 9;                 // mt*2+kk
        int mt = fr >> 1, kk = fr & 1;
        int r  = ii & 511;
        int l  = r >> 3, j = r & 7;
        int m  = mt * 16 + (l & 15);
        int k  = kk * 32 + ((l >> 4) << 3) + j;
        wh[i] = (m < 62 && k < 62) ? (_Float16)Vs[m * 62 + k] : (_Float16)0.f;
    } else if (i < 21252) {
        int ii = i - 17408;
        int v = ii / 62, u = ii - v * 62;
        wh[i] = (_Float16)bs[u * 62 + v];
    }
    if (i < 2) out[SL_OFF + i] = 0.f;
}

// NUMERIC CONTRACT: f16 allowed on gcn/G surface, C1/C2 MFMA inputs, and Sm inputs
// (Vs/sig/bs). Softmax itself stays f32.
__launch_bounds__(256)
__attribute__((amdgpu_waves_per_eu(3, 3)))   // pin RA to 85-VGPR budget (3 waves/SIMD)
__global__ void stgcn_kernel(
    const float* __restrict__ x,     const float* __restrict__ U1,
    const float* __restrict__ U2,    const float* __restrict__ U3,
    const float* __restrict__ be,    const float* __restrict__ Ve,
    const float* __restrict__ W1,    const float* __restrict__ W2,
    const float* __restrict__ W3,    const float* __restrict__ bs,
    const float* __restrict__ Vs,    const float* __restrict__ a,
    const float* __restrict__ Theta, const _Float16* __restrict__ Wh,
    const float* __restrict__ tb,    const float* __restrict__ rw,
    const float* __restrict__ rb,    const float* __restrict__ gamma_,
    const float* __restrict__ beta_, float* __restrict__ out)
{
    // LDS: 930 + 3844 + 3844 + 1132 = 9750 floats = 39,000 B -> 3 blocks/CU (VGPR-capped)
    __shared__ __align__(16) float sx[930];   // x[b] [t][v][f]
    __shared__ __align__(16) float sS[3844];  // sigT f16 -> tmpS -> C1n(f32) ; F: sC1h/pb0 | sGh @bytes[8192,14336)
    __shared__ __align__(16) float sAt[3844]; // Sm(raw f32) -> C2(f32) ; F: sC2h/pb1 f16 [0,8K)
    __shared__ __align__(16) float sU[1132];  // scratch union

    // stage B/C view of sU
    float* const sL    = sU;          // 186
    float* const sR    = sU + 186;    // 186
    float* const sR0   = sU + 372;    // 186
    float* const sRr   = sU + 558;    // 186
    float* const sy    = sU + 744;    // 15
    float* const sprod = sU + 759;    // 9
    float* const sE    = sU + 768;    // 9
    float* const stA   = sU + 777;    // 9
    // phase2/3/4 partials view (B/C scratch dead)
    float* const pMq   = sU;          // [4][64] per-wave col max   (written in Sm-MFMA block)
    float* const pSq   = sU + 256;    // [4][64] per-wave col expsum
    float* const pCp   = sU + 512;    // [4][64] colsum partials
    float* const pM    = sU + 768;    // 62 final col max
    float* const pInv  = sU + 832;    // 62 1/den
    // persistent tail of sU
    float* const sDiag = sU + 992;    // 62
    float* const scol  = sU + 1054;   // 62
    float* const sred  = sU + 1116;   // 16

    // overlays
    _Float16* const sigT = (_Float16*)sS;          // [64][72] f16 sig^T (B-operand for Sm-MFMA)
    _Float16* const sC1h = (_Float16*)sS;          // [64][64] f16 A-operand (C1n), bytes [0,8192)
    _Float16* const sC2h = (_Float16*)sAt;         // [64][64] f16 A-operand (C2), bytes [0,8192)
    _Float16* const pb0  = (_Float16*)sS;          // gcn ping-pong buffer 0 (after sC1h dead)
    _Float16* const pb1  = (_Float16*)sAt;         // gcn ping-pong buffer 1 (after sC2h dead)
    _Float16* const sGh  = (_Float16*)(sS + 2048); // [3][64][16] f16 G (A-operand for step2)
    _Float16* const XbT  = (_Float16*)sU;          // [16][64] f16 B-operand X^T (over dead pMq/pSq after phase3)

    const int b   = blockIdx.x;
    const int tid = threadIdx.x;
    const int o   = tid & 63;
    const int q   = tid >> 6;
    const int qu  = __builtin_amdgcn_readfirstlane(q);
    const int lane = o;
    const int lo  = lane & 15, hi = lane >> 4;

    // ---- stage A: loads (float2-vectorized) ----
    {
        const float2* xs = reinterpret_cast<const float2*>(x + (size_t)b * 930);
        float2* sd = reinterpret_cast<float2*>(sx);
        for (int i = tid; i < 465; i += 256) sd[i] = xs[i];
    }
    __syncthreads();

    // ---- stage B: temporal attention ----
    if (tid < 15) {
        int t = tid / 5, f = tid % 5;
        float s = 0.f;
        for (int v = 0; v < 62; ++v) s += sx[t * 310 + v * 5 + f] * U1[v];
        sy[tid] = s;
    }
    if (tid < 186) {
        int v = tid / 3, t = tid % 3;
        float s = 0.f, s0 = 0.f;
        #pragma unroll
        for (int f = 0; f < 5; ++f) {
            float xv = sx[t * 310 + v * 5 + f];
            s  += U3[f] * xv;
            s0 += W3[f] * xv;
        }
        sR[v * 3 + t]  = s;
        sR0[t * 62 + v] = s0;
    }
    __syncthreads();
    if (tid < 186) {
        int t = tid / 62, u = tid % 62;
        float s = 0.f;
        for (int f = 0; f < 5; ++f) s += sy[t * 5 + f] * U2[f * 62 + u];
        sL[t * 62 + u] = s;
    }
    __syncthreads();
    // prod -> E -> temporal softmax: wave-0-only, wave-synchronous
    if (tid < 64) {
        if (o < 9) {
            int t = o / 3, u = o - (o / 3) * 3;
            float s = 0.f;
            for (int v = 0; v < 62; ++v) s += sL[t * 62 + v] * sR[v * 3 + u];
            sprod[o] = s;
        }
        WFENCE();
        if (o < 9) {
            int t = o / 3, u = o - (o / 3) * 3;
            float s = 0.f;
            #pragma unroll
            for (int ss = 0; ss < 3; ++ss) {
                float p = sprod[ss * 3 + u] + be[ss * 3 + u];
                s += Ve[t * 3 + ss] * (1.f / (1.f + __expf(-p)));
            }
            sE[o] = s;
        }
        WFENCE();
        if (o < 3) {
            int u = o;
            float m = fmaxf(fmaxf(sE[u], sE[3 + u]), sE[6 + u]);
            float e0 = __expf(sE[u] - m);
            float e1 = __expf(sE[3 + u] - m);
            float e2 = __expf(sE[6 + u] - m);
            float inv = 1.f / (e0 + e1 + e2);
            stA[u]     = e0 * inv;
            stA[3 + u] = e1 * inv;
            stA[6 + u] = e2 * inv;
        }
    }
    __syncthreads();

    // ---- stage C: spatial attention (x_TAt factored out) ----
    if (tid < 186) {
        float w1t[3];
        #pragma unroll
        for (int t = 0; t < 3; ++t) {
            float s = 0.f;
            #pragma unroll
            for (int u = 0; u < 3; ++u) s += W1[u] * stA[t * 3 + u];
            w1t[t] = s;
        }
        int v = tid / 3, s3 = tid - v * 3;
        float s = 0.f;
        #pragma unroll
        for (int f = 0; f < 5; ++f) {
            float z = 0.f;
            #pragma unroll
            for (int t = 0; t < 3; ++t) z += sx[t * 310 + v * 5 + f] * w1t[t];
            s += z * W2[f * 3 + s3];
        }
        sL[v * 3 + s3] = s * INV_SQRT310;
        int u2 = tid / 62, v2 = tid - u2 * 62;
        float s2 = 0.f;
        #pragma unroll
        for (int t = 0; t < 3; ++t) s2 += stA[t * 3 + u2] * sR0[t * 62 + v2];
        sRr[u2 * 62 + v2] = s2 * INV_SQRT310;
    }
    __syncthreads();
    // sig[w][v] -> f16 TRANSPOSED sigT[v][w] (B-operand for Sm-MFMA); bsT coalesced
    {
        const _Float16* bsT = Wh + 17408;
        for (int i = tid; i < 3844; i += 256) {
            int v = i / 62, w = i - v * 62;
            float s = (float)bsT[i];                       // bsT[v*62+w] = bs[w*62+v]
            #pragma unroll
            for (int t = 0; t < 3; ++t) s += sL[w * 3 + t] * sRr[t * 62 + v];
            sigT[v * 72 + w] = (_Float16)(1.f / (1.f + __expf(-s)));
        }
        // zero K-pads w=62,63 for every row
        if (tid < 64) {
            sigT[tid * 72 + 62] = (_Float16)0.f;
            sigT[tid * 72 + 63] = (_Float16)0.f;
        }
    }
    __syncthreads();
    // ---- Sm = Vs·sig via MFMA, softmax column stats folded in-register (R18) ----
    {
        const f16x8* VsAp = (const f16x8*)(Wh + 13312);
        f16x8 A0 = VsAp[(qu * 2 + 0) * 64 + lane];
        f16x8 A1 = VsAp[(qu * 2 + 1) * 64 + lane];
        #pragma unroll
        for (int nt = 0; nt < 4; ++nt) {
            f16x8 B0 = *(const f16x8*)(sigT + (nt * 16 + lo) * 72 + (hi << 3));
            f16x8 B1 = *(const f16x8*)(sigT + (nt * 16 + lo) * 72 + 32 + (hi << 3));
            f32x4 D = (f32x4){0.f, 0.f, 0.f, 0.f};
            D = __builtin_amdgcn_mfma_f32_16x16x32_f16(A0, B0, D, 0, 0, 0);
            D = __builtin_amdgcn_mfma_f32_16x16x32_f16(A1, B1, D, 0, 0, 0);
            int v  = nt * 16 + lo;
            int ub = qu * 16 + (hi << 2);
            #pragma unroll
            for (int rg = 0; rg < 4; ++rg) {
                if (ub + rg < 62 && v < 62) sAt[(ub + rg) * 62 + v] = D[rg];   // RAW Sm f32
            }
            float mq = -1e30f;
            #pragma unroll
            for (int rg = 0; rg < 4; ++rg) mq = fmaxf(mq, (ub + rg < 62) ? D[rg] : -1e30f);
            mq = fmaxf(mq, __shfl_xor(mq, 16, 64));
            mq = fmaxf(mq, __shfl_xor(mq, 32, 64));
            float sq = 0.f;
            #pragma unroll
            for (int rg = 0; rg < 4; ++rg) if (ub + rg < 62) sq += __expf(D[rg] - mq);
            sq += __shfl_xor(sq, 16, 64);
            sq += __shfl_xor(sq, 32, 64);
            if (hi == 0 && v < 62) { pMq[qu * 64 + v] = mq; pSq[qu * 64 + v] = sq; }
        }
    }
    __syncthreads();

    // ---- phase 2: tmpS (column-mapped, colsum free) + dloss ----
    {
        int j = o;
        if (j < 62) {
            int i0 = qu * 16, i1 = (qu == 3) ? 62 : i0 + 16;
            float xj[5];
            #pragma unroll
            for (int f = 0; f < 5; ++f) xj[f] = sx[310 + j * 5 + f];
            float cp2 = 0.f;
            for (int i = i0; i < i1; ++i) {
                float s = 0.f;
                #pragma unroll
                for (int f = 0; f < 5; ++f)
                    s += fabsf(sx[310 + i * 5 + f] - xj[f]) * a[f];
                float e = __expf(fmaxf(s, 0.f));
                sS[i * 62 + j] = e;                        // tmpS overwrites sigT
                cp2 += e;
            }
            pCp[qu * 64 + j] = cp2;
        } else {
            int f = (o == 62) ? qu : (qu == 0 ? 4 : -1);
            if (f >= 0) {
                float su = 0.f, sq2 = 0.f;
                for (int v = 0; v < 62; ++v) {
                    float xv = sx[310 + v * 5 + f];
                    su += xv; sq2 += xv * xv;
                }
                sred[8 + f] = 124.f * sq2 - 2.f * su * su;
            }
        }
    }
    __syncthreads();
    // ---- phase 3: per-column combines ----
    if (tid < 62) {
        int v = tid;
        float m0 = pMq[v], m1 = pMq[64 + v], m2 = pMq[128 + v], m3 = pMq[192 + v];
        float M = fmaxf(fmaxf(m0, m1), fmaxf(m2, m3));
        float den = pSq[v] * __expf(m0 - M) + pSq[64 + v] * __expf(m1 - M)
                  + pSq[128 + v] * __expf(m2 - M) + pSq[192 + v] * __expf(m3 - M);
        pM[v]   = M;
        pInv[v] = 1.f / den;
        scol[v] = 1.f / (pCp[v] + pCp[64 + v] + pCp[128 + v] + pCp[192 + v]);
    }
    __syncthreads();
    // ---- phase 4: normalize S, fused softmax-At, C1n/C2 f32 in place, Sloss ----
    float slp = 0.f;
    for (int idx = tid; idx < 3844; idx += 256) {
        int i = idx / 62, j = idx - i * 62;
        float sv = sS[idx] * scol[j];
        out[S_OFF + (size_t)b * 3844 + idx] = sv;
        slp += sv * sv;
        float A = __expf(sAt[idx] - pM[j]) * pInv[j];
        if (i == j) sDiag[i] = A;
        sS[idx] = -sv * A;                              // C1 PRE-NEGATED (f32)
        float c2 = 2.f * sv * sv; if (i == j) c2 -= 1.f;
        sAt[idx] = c2 * A;                              // C2 (f32)
    }
    for (int m = 32; m > 0; m >>= 1) slp += __shfl_down(slp, m, 64);
    if ((tid & 63) == 0) sred[q] = slp;
    __syncthreads();
    if (tid == 0) {
        atomicAdd(out + SL_OFF, (sred[0] + sred[1] + sred[2] + sred[3]) * (ALPHA_F / 2048.f));
        float dl = sred[8] + sred[9] + sred[10] + sred[11] + sred[12];
        atomicAdd(out + DL_OFF, dl * ALPHA_F);
    }

    // ---- conversion: f32 C -> f16 swizzled A-operands, race-free 2-phase overlay (R14) ----
    {
        unsigned cp8[8];
        #pragma unroll
        for (int it = 0; it < 8; ++it) {
            int idx = tid + it * 256;                      // 0..2047
            union { _Float16 h[2]; unsigned u; } pk;
            pk.h[0] = (_Float16)sS[idx];
            pk.h[1] = (_Float16)sAt[idx];
            cp8[it] = pk.u;
        }
        __syncthreads();
        #pragma unroll
        for (int it = 0; it < 8; ++it) {
            int idx = tid + it * 256;
            int i = idx / 62, j = idx - i * 62;
            int ad = j * 64 + (i ^ ((j & 7) << 3));        // A-layout: row=v(j), k=u(i)
            union { _Float16 h[2]; unsigned u; } pk; pk.u = cp8[it];
            sC1h[ad] = pk.h[0];
            sC2h[ad] = pk.h[1];
        }
        #pragma unroll
        for (int it = 8; it < 16; ++it) {
            int idx = tid + it * 256;
            if (idx < 3844) {
                float c1 = sS[idx], c2v = sAt[idx];
                int i = idx / 62, j = idx - i * 62;
                int ad = j * 64 + (i ^ ((j & 7) << 3));
                sC1h[ad] = (_Float16)c1;
                sC2h[ad] = (_Float16)c2v;
            }
        }
        // zero the 2 unwritten k-slots (u=62,63) per row: no garbage into MFMA K-dim
        if (tid < 124) {
            int j = tid >> 1, i = 62 + (tid & 1);
            int ad = j * 64 + (i ^ ((j & 7) << 3));
            sC1h[ad] = (_Float16)0.f;
            sC2h[ad] = (_Float16)0.f;
        }
    }
    __syncthreads();

    // ---- build: XbT (f16 B-operand X^T) + g0 (f16) into sGh + kf=15 zero ----
    for (int i = tid; i < 930; i += 256) {
        int t = i / 310, r = i - t * 310, n = r / 5, f = r - n * 5;
        int tf = t * 5 + f;
        float xv = sx[i];
        XbT[tf * 64 + (n ^ ((tf & 7) << 3))] = (_Float16)xv;
        sGh[t * 1024 + n * 16 + f] = (_Float16)(sDiag[n] * xv);   // g0 = diag·x (kf 0..4)
    }
    if (tid < 192) {   // zero kf=15 for all rows (K-dim garbage guard for step2 MFMA)
        int t = tid >> 6, v = tid & 63;
        sGh[t * 1024 + v * 16 + 15] = (_Float16)0.f;
    }
    if (tid < 30) {                       // zero XbT k-holes u in {62,63}, rows tf 0..14
        int tf = tid >> 1, u2 = 62 + (tid & 1);
        XbT[tf * 64 + (u2 ^ ((tf & 7) << 3))] = (_Float16)0.f;
    }
    if (tid >= 64 && tid < 128) XbT[15 * 64 + (tid - 64)] = (_Float16)0.f;   // pad row tf=15
    __syncthreads();

    // ---- step1 as MFMA: G1 = C1n^T·X, G2 = C2^T·X, all 3 t at once (4 mfma/wave).
    //      D-scatter (f16, bytes >=8K) disjoint from A-reads (<8K): no intra-phase barrier. ----
    {
        int r0 = qu * 16 + lo;                // A row = v
        int sw = (r0 & 7) << 3;
        int cb = hi << 3;
        int bsw = (lo & 7) << 3;
        f32x4 D1 = (f32x4){0.f, 0.f, 0.f, 0.f};
        f32x4 D2 = (f32x4){0.f, 0.f, 0.f, 0.f};
        #pragma unroll
        for (int kk = 0; kk < 2; ++kk) {
            int ko = kk * 32 + cb;
            f16x8 Bf = *(const f16x8*)(XbT + lo * 64 + (ko ^ bsw));
            f16x8 A1 = *(const f16x8*)(sC1h + r0 * 64 + (ko ^ sw));
            f16x8 A2 = *(const f16x8*)(sC2h + r0 * 64 + (ko ^ sw));
            D1 = __builtin_amdgcn_mfma_f32_16x16x32_f16(A1, Bf, D1, 0, 0, 0);
            D2 = __builtin_amdgcn_mfma_f32_16x16x32_f16(A2, Bf, D2, 0, 0, 0);
        }
        int tf = lo;
        if (tf < 15) {
            int t = tf / 5, f = tf - (tf / 5) * 5;
            int vb = qu * 16 + (hi << 2);
            #pragma unroll
            for (int rg = 0; rg < 4; ++rg) {
                int v = vb + rg;
                if (v < 62) {
                    sGh[t * 1024 + v * 16 + 5 + f]  = (_Float16)D1[rg];
                    sGh[t * 1024 + v * 16 + 10 + f] = (_Float16)D2[rg];
                }
            }
        }
    }
    __syncthreads();

    // ---- stage F t-loop, ping-pong pipelined:
    //      step2(0)->pb0 | bar | {step2(1)->pb1 ∥ step3(0)<-pb0} | bar |
    //      {step2(2)->pb0 ∥ step3(1)<-pb1} | bar | step3(2)<-pb0
    //      (5 barriers -> 3; step2 VALU scatter co-scheduled with step3 MFMAs) ----
    const f16x8* Wp  = (const f16x8*)Wh;
    const _Float16* Thp = Wh + 12288;          // Theta B-frags (16x16x16 layout)
    f16x4 thB[4];
    #pragma unroll
    for (int ot = 0; ot < 4; ++ot)
        thB[ot] = *(const f16x4*)(Thp + ot * 256 + lane * 4);

    f32x4 acc[4];
    #pragma unroll
    for (int ot = 0; ot < 4; ++ot) acc[ot] = (f32x4){0.f, 0.f, 0.f, 0.f};

    // zero pad rows 62,63 of BOTH ping-pong buffers (sC1h/sC2h dead after step1 barrier)
    if (tid < 128) pb0[62 * 64 + tid] = (_Float16)0.f;
    else           pb1[62 * 64 + (tid - 128)] = (_Float16)0.f;

    auto STEP2 = [&](int t, _Float16* pb) {
        f16x4 Ag = *(const f16x4*)(sGh + t * 1024 + (qu * 16 + lo) * 16 + (hi << 2));
        f32x4 Dg[4];
        #pragma unroll
        for (int ot = 0; ot < 4; ++ot) {
            f32x4 zero = (f32x4){0.f, 0.f, 0.f, 0.f};
            Dg[ot] = __builtin_amdgcn_mfma_f32_16x16x16f16(Ag, thB[ot], zero, 0, 0, 0);
        }
        #pragma unroll
        for (int rg = 0; rg < 4; ++rg) {
            int v = qu * 16 + (hi << 2) + rg;
            int swv = (v & 7) << 3;
            #pragma unroll
            for (int ot = 0; ot < 4; ++ot) {
                int oc = ot * 16 + lo;
                pb[v * 64 + (oc ^ swv)] = (_Float16)fmaxf(Dg[ot][rg], 0.f);
            }
        }
    };
    auto STEP3 = [&](int t, const _Float16* pb) {
        int r0 = qu * 16 + lo;
        int cb = hi << 3;
        int sw = (r0 & 7) << 3;
        f16x8 A0 = *(const f16x8*)(pb + r0 * 64 + ((cb) ^ sw));
        f16x8 A1 = *(const f16x8*)(pb + r0 * 64 + ((32 + cb) ^ sw));
        #pragma unroll
        for (int ot = 0; ot < 4; ++ot) {
            f16x8 B0 = Wp[((t * 4 + ot) * 2 + 0) * 64 + lane];
            f16x8 B1 = Wp[((t * 4 + ot) * 2 + 1) * 64 + lane];
            acc[ot] = __builtin_amdgcn_mfma_f32_16x16x32_f16(A0, B0, acc[ot], 0, 0, 0);
            acc[ot] = __builtin_amdgcn_mfma_f32_16x16x32_f16(A1, B1, acc[ot], 0, 0, 0);
        }
    };

    STEP2(0, pb0);
    __syncthreads();
    STEP2(1, pb1);   // writes pb1, disjoint from step3(0)'s pb0 reads
    STEP3(0, pb0);
    __syncthreads();
    STEP2(2, pb0);   // pb0 reads of step3(0) are barrier-separated
    STEP3(1, pb1);
    __syncthreads();
    STEP3(2, pb0);

    // ---- fragment-direct epilogue: z + LayerNorm straight from acc registers ----
    {
        float rbv[4], tbv[4], gmv[4], btv[4], rww[4][5];
        #pragma unroll
        for (int ot = 0; ot < 4; ++ot) {
            int oo = ot * 16 + lo;
            rbv[ot] = rb[oo]; tbv[ot] = tb[oo];
            gmv[ot] = gamma_[oo]; btv[ot] = beta_[oo];
            #pragma unroll
            for (int f = 0; f < 5; ++f) rww[ot][f] = rw[oo * 5 + f];
        }
        float zst[4][4];                      // [rg][ot]
        float s1[4] = {0.f, 0.f, 0.f, 0.f};
        float s2[4] = {0.f, 0.f, 0.f, 0.f};
        #pragma unroll
        for (int rg = 0; rg < 4; ++rg) {
            int v = qu * 16 + hi * 4 + rg;    // may be 62/63 (wave 3): stores guarded below
            float x5[5];
            #pragma unroll
            for (int f = 0; f < 5; ++f) x5[f] = sx[v * 5 + f];   // x[:,0]
            #pragma unroll
            for (int ot = 0; ot < 4; ++ot) {
                float r = rbv[ot];
                #pragma unroll
                for (int f = 0; f < 5; ++f) r += x5[f] * rww[ot][f];
                float z = fmaxf(r + (acc[ot][rg] + tbv[ot]) * INV_SQRT15, 0.f);
                zst[rg][ot] = z;
                s1[rg] += z;
                s2[rg] += z * z;
            }
        }
        #pragma unroll
        for (int rg = 0; rg < 4; ++rg) {
            #pragma unroll
            for (int m = 1; m < 16; m <<= 1) {
                s1[rg] += __shfl_xor(s1[rg], m, 64);
                s2[rg] += __shfl_xor(s2[rg], m, 64);
            }
        }
        #pragma unroll
        for (int rg = 0; rg < 4; ++rg) {
            int v = qu * 16 + hi * 4 + rg;
            float mean = s1[rg] * 0.015625f;
            float var  = s2[rg] * 0.015625f - mean * mean;
            float inv  = rsqrtf(var + 1e-5f);
            if (v < 62) {
                #pragma unroll
                for (int ot = 0; ot < 4; ++ot) {
                    int oo = ot * 16 + lo;
                    out[XR_OFF + (size_t)b * 3968 + v * 64 + oo] =
                        (zst[rg][ot] - mean) * inv * gmv[ot] + btv[ot];
                }
            }
        }
    }
}

extern "C" void kernel_launch(void* const* d_in, const int* in_sizes, int n_in,
                              void* d_out, int out_size, void* d_ws, size_t ws_size,
                              hipStream_t stream) {
    const float* x   = (const float*)d_in[0];
    const float* U1  = (const float*)d_in[1];
    const float* U2  = (const float*)d_in[2];
    const float* U3  = (const float*)d_in[3];
    const float* be  = (const float*)d_in[4];
    const float* Ve  = (const float*)d_in[5];
    const float* W1  = (const float*)d_in[6];
    const float* W2  = (const float*)d_in[7];
    const float* W3  = (const float*)d_in[8];
    const float* bs  = (const float*)d_in[9];
    const float* Vs  = (const float*)d_in[10];
    const float* a   = (const float*)d_in[11];
    const float* Th  = (const float*)d_in[12];
    const float* tw  = (const float*)d_in[13];
    const float* tb  = (const float*)d_in[14];
    const float* rw  = (const float*)d_in[15];
    const float* rb  = (const float*)d_in[16];
    const float* gm  = (const float*)d_in[17];
    const float* bt  = (const float*)d_in[18];
    float* out = (float*)d_out;
    _Float16* wh = (_Float16*)d_ws;  // 21252 f16 = 42504 B (tw + Theta + VsA + bsT)

    prep_kernel<<<84, 256, 0, stream>>>(tw, Th, Vs, bs, wh, out);
    stgcn_kernel<<<2048, 256, 0, stream>>>(x, U1, U2, U3, be, Ve, W1, W2, W3,
                                           bs, Vs, a, Th, wh, tb, rw, rb, gm, bt, out);
}

// Round 20
// 190.453 us; speedup vs baseline: 1.0277x; 1.0138x over previous
//
#include <hip/hip_runtime.h>

// Problem constants
#define BB 2048
#define TT 3
#define VV 62
#define FF 5
#define HH 64

// Output layout (flat, return order): x_residual[2048*62*64], Sloss, dloss, S[2048*62*62]
#define XR_OFF 0
#define SL_OFF 8126464
#define DL_OFF 8126465
#define S_OFF  8126466

#define ALPHA_F 1e-4f
#define INV_SQRT310 0.05679618342470648f  // 1/sqrt(62*5)
#define INV_SQRT15  0.2581988897471611f   // 1/sqrt(3*5)

typedef float f32x2 __attribute__((ext_vector_type(2)));
typedef float f32x4 __attribute__((ext_vector_type(4)));
typedef _Float16 f16x4 __attribute__((ext_vector_type(4)));
typedef _Float16 f16x8 __attribute__((ext_vector_type(8)));

// compiler-ordering fence for wave-synchronous LDS phases
#define WFENCE() do { __builtin_amdgcn_wave_barrier(); __asm__ __volatile__("" ::: "memory"); } while (0)

// Prep (workspace f16, 21252 elems = 42504 B):
//  [0,12288)      tw -> f16 B-frags (16x16x32), as R8
//  [12288,13312)  Theta -> f16 B-frags (16x16x16)
//  [13312,17408)  Vs -> f16 A-frags (16x16x32), 0-padded m>=62 / k>=62
//  [17408,21252)  bsT f16: bsT[v*62+u] = bs[u*62+v]
__global__ void prep_kernel(const float* __restrict__ tw, const float* __restrict__ Theta,
                            const float* __restrict__ Vs, const float* __restrict__ bs,
                            _Float16* __restrict__ wh, float* __restrict__ out) {
    int i = blockIdx.x * 256 + threadIdx.x;
    if (i < 12288) {
        int t  = i / 4096, r2 = i - t * 4096;
        int ot = r2 >> 10, r3 = r2 & 1023;
        int kk = r3 >> 9,  r4 = r3 & 511;
        int l  = r4 >> 3,  j  = r4 & 7;
        int o  = ot * 16 + (l & 15);
        int c  = kk * 32 + ((l >> 4) << 3) + j;
        wh[i] = (_Float16)tw[o * 192 + c * 3 + t];
    } else if (i < 13312) {
        int ii = i - 12288;
        int ot = ii >> 8, r = ii & 255;
        int l  = r >> 2,  j = r & 3;
        int k  = ((l >> 4) << 2) + j;
        int o  = ot * 16 + (l & 15);
        wh[i] = (k < 15) ? (_Float16)Theta[k * 64 + o] : (_Float16)0.f;
    } else if (i < 17408) {
        int ii = i - 13312;
        int fr = ii >> 9;                 // mt*2+kk
        int mt = fr >> 1, kk = fr & 1;
        int r  = ii & 511;
        int l  = r >> 3, j = r & 7;
        int m  = mt * 16 + (l & 15);
        int k  = kk * 32 + ((l >> 4) << 3) + j;
        wh[i] = (m < 62 && k < 62) ? (_Float16)Vs[m * 62 + k] : (_Float16)0.f;
    } else if (i < 21252) {
        int ii = i - 17408;
        int v = ii / 62, u = ii - v * 62;
        wh[i] = (_Float16)bs[u * 62 + v];
    }
    if (i < 2) out[SL_OFF + i] = 0.f;
}

// NUMERIC CONTRACT: f16 allowed on gcn/G surface, C1/C2 MFMA inputs, and Sm inputs
// (Vs/sig/bs). Softmax itself stays f32.
__launch_bounds__(256)
__attribute__((amdgpu_waves_per_eu(4, 4)))   // R20: pin RA to 64 VGPR -> 4 waves/SIMD (demand was 68; 4-reg squeeze)
__global__ void stgcn_kernel(
    const float* __restrict__ x,     const float* __restrict__ U1,
    const float* __restrict__ U2,    const float* __restrict__ U3,
    const float* __restrict__ be,    const float* __restrict__ Ve,
    const float* __restrict__ W1,    const float* __restrict__ W2,
    const float* __restrict__ W3,    const float* __restrict__ bs,
    const float* __restrict__ Vs,    const float* __restrict__ a,
    const float* __restrict__ Theta, const _Float16* __restrict__ Wh,
    const float* __restrict__ tb,    const float* __restrict__ rw,
    const float* __restrict__ rb,    const float* __restrict__ gamma_,
    const float* __restrict__ beta_, float* __restrict__ out)
{
    // LDS: 930 + 3844 + 3844 + 1132 = 9750 floats = 39,000 B -> 4 blocks/CU if VGPR<=64
    __shared__ __align__(16) float sx[930];   // x[b] [t][v][f]
    __shared__ __align__(16) float sS[3844];  // sigT f16 -> tmpS -> C1n(f32) ; F: sC1h/pb0 | sGh @bytes[8192,14336)
    __shared__ __align__(16) float sAt[3844]; // Sm(raw f32) -> C2(f32) ; F: sC2h/pb1 f16 [0,8K)
    __shared__ __align__(16) float sU[1132];  // scratch union

    // stage B/C view of sU
    float* const sL    = sU;          // 186
    float* const sR    = sU + 186;    // 186
    float* const sR0   = sU + 372;    // 186
    float* const sRr   = sU + 558;    // 186
    float* const sy    = sU + 744;    // 15
    float* const sprod = sU + 759;    // 9
    float* const sE    = sU + 768;    // 9
    float* const stA   = sU + 777;    // 9
    // phase2/3/4 partials view (B/C scratch dead)
    float* const pMq   = sU;          // [4][64] per-wave col max   (written in Sm-MFMA block)
    float* const pSq   = sU + 256;    // [4][64] per-wave col expsum
    float* const pCp   = sU + 512;    // [4][64] colsum partials
    float* const pM    = sU + 768;    // 62 final col max
    float* const pInv  = sU + 832;    // 62 1/den
    // persistent tail of sU
    float* const sDiag = sU + 992;    // 62
    float* const scol  = sU + 1054;   // 62
    float* const sred  = sU + 1116;   // 16

    // overlays
    _Float16* const sigT = (_Float16*)sS;          // [64][72] f16 sig^T (B-operand for Sm-MFMA)
    _Float16* const sC1h = (_Float16*)sS;          // [64][64] f16 A-operand (C1n), bytes [0,8192)
    _Float16* const sC2h = (_Float16*)sAt;         // [64][64] f16 A-operand (C2), bytes [0,8192)
    _Float16* const pb0  = (_Float16*)sS;          // gcn ping-pong buffer 0 (after sC1h dead)
    _Float16* const pb1  = (_Float16*)sAt;         // gcn ping-pong buffer 1 (after sC2h dead)
    _Float16* const sGh  = (_Float16*)(sS + 2048); // [3][64][16] f16 G (A-operand for step2)
    _Float16* const XbT  = (_Float16*)sU;          // [16][64] f16 B-operand X^T (over dead pMq/pSq after phase3)

    const int b   = blockIdx.x;
    const int tid = threadIdx.x;
    const int o   = tid & 63;
    const int q   = tid >> 6;
    const int qu  = __builtin_amdgcn_readfirstlane(q);
    const int lane = o;
    const int lo  = lane & 15, hi = lane >> 4;

    // ---- stage A: loads (float2-vectorized) ----
    {
        const float2* xs = reinterpret_cast<const float2*>(x + (size_t)b * 930);
        float2* sd = reinterpret_cast<float2*>(sx);
        for (int i = tid; i < 465; i += 256) sd[i] = xs[i];
    }
    __syncthreads();

    // ---- stage B: temporal attention ----
    if (tid < 15) {
        int t = tid / 5, f = tid % 5;
        float s = 0.f;
        for (int v = 0; v < 62; ++v) s += sx[t * 310 + v * 5 + f] * U1[v];
        sy[tid] = s;
    }
    if (tid < 186) {
        int v = tid / 3, t = tid % 3;
        float s = 0.f, s0 = 0.f;
        #pragma unroll
        for (int f = 0; f < 5; ++f) {
            float xv = sx[t * 310 + v * 5 + f];
            s  += U3[f] * xv;
            s0 += W3[f] * xv;
        }
        sR[v * 3 + t]  = s;
        sR0[t * 62 + v] = s0;
    }
    __syncthreads();
    if (tid < 186) {
        int t = tid / 62, u = tid % 62;
        float s = 0.f;
        for (int f = 0; f < 5; ++f) s += sy[t * 5 + f] * U2[f * 62 + u];
        sL[t * 62 + u] = s;
    }
    __syncthreads();
    // prod -> E -> temporal softmax: wave-0-only, wave-synchronous
    if (tid < 64) {
        if (o < 9) {
            int t = o / 3, u = o - (o / 3) * 3;
            float s = 0.f;
            for (int v = 0; v < 62; ++v) s += sL[t * 62 + v] * sR[v * 3 + u];
            sprod[o] = s;
        }
        WFENCE();
        if (o < 9) {
            int t = o / 3, u = o - (o / 3) * 3;
            float s = 0.f;
            #pragma unroll
            for (int ss = 0; ss < 3; ++ss) {
                float p = sprod[ss * 3 + u] + be[ss * 3 + u];
                s += Ve[t * 3 + ss] * (1.f / (1.f + __expf(-p)));
            }
            sE[o] = s;
        }
        WFENCE();
        if (o < 3) {
            int u = o;
            float m = fmaxf(fmaxf(sE[u], sE[3 + u]), sE[6 + u]);
            float e0 = __expf(sE[u] - m);
            float e1 = __expf(sE[3 + u] - m);
            float e2 = __expf(sE[6 + u] - m);
            float inv = 1.f / (e0 + e1 + e2);
            stA[u]     = e0 * inv;
            stA[3 + u] = e1 * inv;
            stA[6 + u] = e2 * inv;
        }
    }
    __syncthreads();

    // ---- stage C: spatial attention (x_TAt factored out) ----
    if (tid < 186) {
        float w1t[3];
        #pragma unroll
        for (int t = 0; t < 3; ++t) {
            float s = 0.f;
            #pragma unroll
            for (int u = 0; u < 3; ++u) s += W1[u] * stA[t * 3 + u];
            w1t[t] = s;
        }
        int v = tid / 3, s3 = tid - v * 3;
        float s = 0.f;
        #pragma unroll
        for (int f = 0; f < 5; ++f) {
            float z = 0.f;
            #pragma unroll
            for (int t = 0; t < 3; ++t) z += sx[t * 310 + v * 5 + f] * w1t[t];
            s += z * W2[f * 3 + s3];
        }
        sL[v * 3 + s3] = s * INV_SQRT310;
        int u2 = tid / 62, v2 = tid - u2 * 62;
        float s2 = 0.f;
        #pragma unroll
        for (int t = 0; t < 3; ++t) s2 += stA[t * 3 + u2] * sR0[t * 62 + v2];
        sRr[u2 * 62 + v2] = s2 * INV_SQRT310;
    }
    __syncthreads();
    // sig[w][v] -> f16 TRANSPOSED sigT[v][w] (B-operand for Sm-MFMA); bsT coalesced
    {
        const _Float16* bsT = Wh + 17408;
        for (int i = tid; i < 3844; i += 256) {
            int v = i / 62, w = i - v * 62;
            float s = (float)bsT[i];                       // bsT[v*62+w] = bs[w*62+v]
            #pragma unroll
            for (int t = 0; t < 3; ++t) s += sL[w * 3 + t] * sRr[t * 62 + v];
            sigT[v * 72 + w] = (_Float16)(1.f / (1.f + __expf(-s)));
        }
        // zero K-pads w=62,63 for every row
        if (tid < 64) {
            sigT[tid * 72 + 62] = (_Float16)0.f;
            sigT[tid * 72 + 63] = (_Float16)0.f;
        }
    }
    __syncthreads();
    // ---- Sm = Vs·sig via MFMA, softmax column stats folded in-register (R18) ----
    {
        const f16x8* VsAp = (const f16x8*)(Wh + 13312);
        f16x8 A0 = VsAp[(qu * 2 + 0) * 64 + lane];
        f16x8 A1 = VsAp[(qu * 2 + 1) * 64 + lane];
        #pragma unroll
        for (int nt = 0; nt < 4; ++nt) {
            f16x8 B0 = *(const f16x8*)(sigT + (nt * 16 + lo) * 72 + (hi << 3));
            f16x8 B1 = *(const f16x8*)(sigT + (nt * 16 + lo) * 72 + 32 + (hi << 3));
            f32x4 D = (f32x4){0.f, 0.f, 0.f, 0.f};
            D = __builtin_amdgcn_mfma_f32_16x16x32_f16(A0, B0, D, 0, 0, 0);
            D = __builtin_amdgcn_mfma_f32_16x16x32_f16(A1, B1, D, 0, 0, 0);
            int v  = nt * 16 + lo;
            int ub = qu * 16 + (hi << 2);
            #pragma unroll
            for (int rg = 0; rg < 4; ++rg) {
                if (ub + rg < 62 && v < 62) sAt[(ub + rg) * 62 + v] = D[rg];   // RAW Sm f32
            }
            float mq = -1e30f;
            #pragma unroll
            for (int rg = 0; rg < 4; ++rg) mq = fmaxf(mq, (ub + rg < 62) ? D[rg] : -1e30f);
            mq = fmaxf(mq, __shfl_xor(mq, 16, 64));
            mq = fmaxf(mq, __shfl_xor(mq, 32, 64));
            float sq = 0.f;
            #pragma unroll
            for (int rg = 0; rg < 4; ++rg) if (ub + rg < 62) sq += __expf(D[rg] - mq);
            sq += __shfl_xor(sq, 16, 64);
            sq += __shfl_xor(sq, 32, 64);
            if (hi == 0 && v < 62) { pMq[qu * 64 + v] = mq; pSq[qu * 64 + v] = sq; }
        }
    }
    __syncthreads();

    // ---- phase 2: tmpS (column-mapped, colsum free) + dloss ----
    {
        int j = o;
        if (j < 62) {
            int i0 = qu * 16, i1 = (qu == 3) ? 62 : i0 + 16;
            float xj[5];
            #pragma unroll
            for (int f = 0; f < 5; ++f) xj[f] = sx[310 + j * 5 + f];
            float cp2 = 0.f;
            for (int i = i0; i < i1; ++i) {
                float s = 0.f;
                #pragma unroll
                for (int f = 0; f < 5; ++f)
                    s += fabsf(sx[310 + i * 5 + f] - xj[f]) * a[f];
                float e = __expf(fmaxf(s, 0.f));
                sS[i * 62 + j] = e;                        // tmpS overwrites sigT
                cp2 += e;
            }
            pCp[qu * 64 + j] = cp2;
        } else {
            int f = (o == 62) ? qu : (qu == 0 ? 4 : -1);
            if (f >= 0) {
                float su = 0.f, sq2 = 0.f;
                for (int v = 0; v < 62; ++v) {
                    float xv = sx[310 + v * 5 + f];
                    su += xv; sq2 += xv * xv;
                }
                sred[8 + f] = 124.f * sq2 - 2.f * su * su;
            }
        }
    }
    __syncthreads();
    // ---- phase 3: per-column combines ----
    if (tid < 62) {
        int v = tid;
        float m0 = pMq[v], m1 = pMq[64 + v], m2 = pMq[128 + v], m3 = pMq[192 + v];
        float M = fmaxf(fmaxf(m0, m1), fmaxf(m2, m3));
        float den = pSq[v] * __expf(m0 - M) + pSq[64 + v] * __expf(m1 - M)
                  + pSq[128 + v] * __expf(m2 - M) + pSq[192 + v] * __expf(m3 - M);
        pM[v]   = M;
        pInv[v] = 1.f / den;
        scol[v] = 1.f / (pCp[v] + pCp[64 + v] + pCp[128 + v] + pCp[192 + v]);
    }
    __syncthreads();
    // ---- phase 4: normalize S, fused softmax-At, C1n/C2 f32 in place, Sloss ----
    float slp = 0.f;
    for (int idx = tid; idx < 3844; idx += 256) {
        int i = idx / 62, j = idx - i * 62;
        float sv = sS[idx] * scol[j];
        out[S_OFF + (size_t)b * 3844 + idx] = sv;
        slp += sv * sv;
        float A = __expf(sAt[idx] - pM[j]) * pInv[j];
        if (i == j) sDiag[i] = A;
        sS[idx] = -sv * A;                              // C1 PRE-NEGATED (f32)
        float c2 = 2.f * sv * sv; if (i == j) c2 -= 1.f;
        sAt[idx] = c2 * A;                              // C2 (f32)
    }
    for (int m = 32; m > 0; m >>= 1) slp += __shfl_down(slp, m, 64);
    if ((tid & 63) == 0) sred[q] = slp;
    __syncthreads();
    if (tid == 0) {
        atomicAdd(out + SL_OFF, (sred[0] + sred[1] + sred[2] + sred[3]) * (ALPHA_F / 2048.f));
        float dl = sred[8] + sred[9] + sred[10] + sred[11] + sred[12];
        atomicAdd(out + DL_OFF, dl * ALPHA_F);
    }

    // ---- conversion: f32 C -> f16 swizzled A-operands, race-free 2-phase overlay (R14) ----
    {
        unsigned cp8[8];
        #pragma unroll
        for (int it = 0; it < 8; ++it) {
            int idx = tid + it * 256;                      // 0..2047
            union { _Float16 h[2]; unsigned u; } pk;
            pk.h[0] = (_Float16)sS[idx];
            pk.h[1] = (_Float16)sAt[idx];
            cp8[it] = pk.u;
        }
        __syncthreads();
        #pragma unroll
        for (int it = 0; it < 8; ++it) {
            int idx = tid + it * 256;
            int i = idx / 62, j = idx - i * 62;
            int ad = j * 64 + (i ^ ((j & 7) << 3));        // A-layout: row=v(j), k=u(i)
            union { _Float16 h[2]; unsigned u; } pk; pk.u = cp8[it];
            sC1h[ad] = pk.h[0];
            sC2h[ad] = pk.h[1];
        }
        #pragma unroll
        for (int it = 8; it < 16; ++it) {
            int idx = tid + it * 256;
            if (idx < 3844) {
                float c1 = sS[idx], c2v = sAt[idx];
                int i = idx / 62, j = idx - i * 62;
                int ad = j * 64 + (i ^ ((j & 7) << 3));
                sC1h[ad] = (_Float16)c1;
                sC2h[ad] = (_Float16)c2v;
            }
        }
        // zero the 2 unwritten k-slots (u=62,63) per row: no garbage into MFMA K-dim
        if (tid < 124) {
            int j = tid >> 1, i = 62 + (tid & 1);
            int ad = j * 64 + (i ^ ((j & 7) << 3));
            sC1h[ad] = (_Float16)0.f;
            sC2h[ad] = (_Float16)0.f;
        }
    }
    __syncthreads();

    // ---- build: XbT (f16 B-operand X^T) + g0 (f16) into sGh + kf=15 zero ----
    for (int i = tid; i < 930; i += 256) {
        int t = i / 310, r = i - t * 310, n = r / 5, f = r - n * 5;
        int tf = t * 5 + f;
        float xv = sx[i];
        XbT[tf * 64 + (n ^ ((tf & 7) << 3))] = (_Float16)xv;
        sGh[t * 1024 + n * 16 + f] = (_Float16)(sDiag[n] * xv);   // g0 = diag·x (kf 0..4)
    }
    if (tid < 192) {   // zero kf=15 for all rows (K-dim garbage guard for step2 MFMA)
        int t = tid >> 6, v = tid & 63;
        sGh[t * 1024 + v * 16 + 15] = (_Float16)0.f;
    }
    if (tid < 30) {                       // zero XbT k-holes u in {62,63}, rows tf 0..14
        int tf = tid >> 1, u2 = 62 + (tid & 1);
        XbT[tf * 64 + (u2 ^ ((tf & 7) << 3))] = (_Float16)0.f;
    }
    if (tid >= 64 && tid < 128) XbT[15 * 64 + (tid - 64)] = (_Float16)0.f;   // pad row tf=15
    __syncthreads();

    // ---- step1 as MFMA: G1 = C1n^T·X, G2 = C2^T·X, all 3 t at once (4 mfma/wave).
    //      D-scatter (f16, bytes >=8K) disjoint from A-reads (<8K): no intra-phase barrier. ----
    {
        int r0 = qu * 16 + lo;                // A row = v
        int sw = (r0 & 7) << 3;
        int cb = hi << 3;
        int bsw = (lo & 7) << 3;
        f32x4 D1 = (f32x4){0.f, 0.f, 0.f, 0.f};
        f32x4 D2 = (f32x4){0.f, 0.f, 0.f, 0.f};
        #pragma unroll
        for (int kk = 0; kk < 2; ++kk) {
            int ko = kk * 32 + cb;
            f16x8 Bf = *(const f16x8*)(XbT + lo * 64 + (ko ^ bsw));
            f16x8 A1 = *(const f16x8*)(sC1h + r0 * 64 + (ko ^ sw));
            f16x8 A2 = *(const f16x8*)(sC2h + r0 * 64 + (ko ^ sw));
            D1 = __builtin_amdgcn_mfma_f32_16x16x32_f16(A1, Bf, D1, 0, 0, 0);
            D2 = __builtin_amdgcn_mfma_f32_16x16x32_f16(A2, Bf, D2, 0, 0, 0);
        }
        int tf = lo;
        if (tf < 15) {
            int t = tf / 5, f = tf - (tf / 5) * 5;
            int vb = qu * 16 + (hi << 2);
            #pragma unroll
            for (int rg = 0; rg < 4; ++rg) {
                int v = vb + rg;
                if (v < 62) {
                    sGh[t * 1024 + v * 16 + 5 + f]  = (_Float16)D1[rg];
                    sGh[t * 1024 + v * 16 + 10 + f] = (_Float16)D2[rg];
                }
            }
        }
    }
    __syncthreads();

    // ---- stage F t-loop, ping-pong pipelined (R19): 3 barriers ----
    const f16x8* Wp  = (const f16x8*)Wh;
    const _Float16* Thp = Wh + 12288;          // Theta B-frags (16x16x16 layout)
    f16x4 thB[4];
    #pragma unroll
    for (int ot = 0; ot < 4; ++ot)
        thB[ot] = *(const f16x4*)(Thp + ot * 256 + lane * 4);

    f32x4 acc[4];
    #pragma unroll
    for (int ot = 0; ot < 4; ++ot) acc[ot] = (f32x4){0.f, 0.f, 0.f, 0.f};

    // zero pad rows 62,63 of BOTH ping-pong buffers (sC1h/sC2h dead after step1 barrier)
    if (tid < 128) pb0[62 * 64 + tid] = (_Float16)0.f;
    else           pb1[62 * 64 + (tid - 128)] = (_Float16)0.f;

    auto STEP2 = [&](int t, _Float16* pb) {
        f16x4 Ag = *(const f16x4*)(sGh + t * 1024 + (qu * 16 + lo) * 16 + (hi << 2));
        f32x4 Dg[4];
        #pragma unroll
        for (int ot = 0; ot < 4; ++ot) {
            f32x4 zero = (f32x4){0.f, 0.f, 0.f, 0.f};
            Dg[ot] = __builtin_amdgcn_mfma_f32_16x16x16f16(Ag, thB[ot], zero, 0, 0, 0);
        }
        #pragma unroll
        for (int rg = 0; rg < 4; ++rg) {
            int v = qu * 16 + (hi << 2) + rg;
            int swv = (v & 7) << 3;
            #pragma unroll
            for (int ot = 0; ot < 4; ++ot) {
                int oc = ot * 16 + lo;
                pb[v * 64 + (oc ^ swv)] = (_Float16)fmaxf(Dg[ot][rg], 0.f);
            }
        }
    };
    auto STEP3 = [&](int t, const _Float16* pb) {
        int r0 = qu * 16 + lo;
        int cb = hi << 3;
        int sw = (r0 & 7) << 3;
        f16x8 A0 = *(const f16x8*)(pb + r0 * 64 + ((cb) ^ sw));
        f16x8 A1 = *(const f16x8*)(pb + r0 * 64 + ((32 + cb) ^ sw));
        #pragma unroll
        for (int ot = 0; ot < 4; ++ot) {
            f16x8 B0 = Wp[((t * 4 + ot) * 2 + 0) * 64 + lane];
            f16x8 B1 = Wp[((t * 4 + ot) * 2 + 1) * 64 + lane];
            acc[ot] = __builtin_amdgcn_mfma_f32_16x16x32_f16(A0, B0, acc[ot], 0, 0, 0);
            acc[ot] = __builtin_amdgcn_mfma_f32_16x16x32_f16(A1, B1, acc[ot], 0, 0, 0);
        }
    };

    STEP2(0, pb0);
    __syncthreads();
    STEP2(1, pb1);   // writes pb1, disjoint from step3(0)'s pb0 reads
    STEP3(0, pb0);
    __syncthreads();
    STEP2(2, pb0);   // pb0 reads of step3(0) are barrier-separated
    STEP3(1, pb1);
    __syncthreads();
    STEP3(2, pb0);

    // ---- fragment-direct epilogue: z + LayerNorm straight from acc registers.
    //      gamma/beta loaded at the writeback loop (short live range — 64-VGPR budget). ----
    {
        float zst[4][4];                      // [rg][ot]
        float s1[4] = {0.f, 0.f, 0.f, 0.f};
        float s2[4] = {0.f, 0.f, 0.f, 0.f};
        {
            float rbv[4], tbv[4], rww[4][5];
            #pragma unroll
            for (int ot = 0; ot < 4; ++ot) {
                int oo = ot * 16 + lo;
                rbv[ot] = rb[oo]; tbv[ot] = tb[oo];
                #pragma unroll
                for (int f = 0; f < 5; ++f) rww[ot][f] = rw[oo * 5 + f];
            }
            #pragma unroll
            for (int rg = 0; rg < 4; ++rg) {
                int v = qu * 16 + hi * 4 + rg;    // may be 62/63 (wave 3): stores guarded below
                float x5[5];
                #pragma unroll
                for (int f = 0; f < 5; ++f) x5[f] = sx[v * 5 + f];   // x[:,0]
                #pragma unroll
                for (int ot = 0; ot < 4; ++ot) {
                    float r = rbv[ot];
                    #pragma unroll
                    for (int f = 0; f < 5; ++f) r += x5[f] * rww[ot][f];
                    float z = fmaxf(r + (acc[ot][rg] + tbv[ot]) * INV_SQRT15, 0.f);
                    zst[rg][ot] = z;
                    s1[rg] += z;
                    s2[rg] += z * z;
                }
            }
        }
        #pragma unroll
        for (int rg = 0; rg < 4; ++rg) {
            #pragma unroll
            for (int m = 1; m < 16; m <<= 1) {
                s1[rg] += __shfl_xor(s1[rg], m, 64);
                s2[rg] += __shfl_xor(s2[rg], m, 64);
            }
        }
        float gmv[4], btv[4];
        #pragma unroll
        for (int ot = 0; ot < 4; ++ot) {
            int oo = ot * 16 + lo;
            gmv[ot] = gamma_[oo]; btv[ot] = beta_[oo];
        }
        #pragma unroll
        for (int rg = 0; rg < 4; ++rg) {
            int v = qu * 16 + hi * 4 + rg;
            float mean = s1[rg] * 0.015625f;
            float var  = s2[rg] * 0.015625f - mean * mean;
            float inv  = rsqrtf(var + 1e-5f);
            if (v < 62) {
                #pragma unroll
                for (int ot = 0; ot < 4; ++ot) {
                    int oo = ot * 16 + lo;
                    out[XR_OFF + (size_t)b * 3968 + v * 64 + oo] =
                        (zst[rg][ot] - mean) * inv * gmv[ot] + btv[ot];
                }
            }
        }
    }
}

extern "C" void kernel_launch(void* const* d_in, const int* in_sizes, int n_in,
                              void* d_out, int out_size, void* d_ws, size_t ws_size,
                              hipStream_t stream) {
    const float* x   = (const float*)d_in[0];
    const float* U1  = (const float*)d_in[1];
    const float* U2  = (const float*)d_in[2];
    const float* U3  = (const float*)d_in[3];
    const float* be  = (const float*)d_in[4];
    const float* Ve  = (const float*)d_in[5];
    const float* W1  = (const float*)d_in[6];
    const float* W2  = (const float*)d_in[7];
    const float* W3  = (const float*)d_in[8];
    const float* bs  = (const float*)d_in[9];
    const float* Vs  = (const float*)d_in[10];
    const float* a   = (const float*)d_in[11];
    const float* Th  = (const float*)d_in[12];
    const float* tw  = (const float*)d_in[13];
    const float* tb  = (const float*)d_in[14];
    const float* rw  = (const float*)d_in[15];
    const float* rb  = (const float*)d_in[16];
    const float* gm  = (const float*)d_in[17];
    const float* bt  = (const float*)d_in[18];
    float* out = (float*)d_out;
    _Float16* wh = (_Float16*)d_ws;  // 21252 f16 = 42504 B (tw + Theta + VsA + bsT)

    prep_kernel<<<84, 256, 0, stream>>>(tw, Th, Vs, bs, wh, out);
    stgcn_kernel<<<2048, 256, 0, stream>>>(x, U1, U2, U3, be, Ve, W1, W2, W3,
                                           bs, Vs, a, Th, wh, tb, rw, rb, gm, bt, out);
}